// Round 11
// baseline (582.527 us; speedup 1.0000x reference)
//
#include <hip/hip_runtime.h>

#define BATCH 512
#define TT 256
#define HH 256
#define HOR 22
#define ROWS 16

typedef __attribute__((ext_vector_type(4))) float f32x4;
typedef __attribute__((ext_vector_type(2))) float f32x2;
// 16-byte aligned pair of 64-bit fragments (aligned 16B aggregate load -> ds_read_b128)
struct __align__(16) lpair { long x, y; };

__device__ __forceinline__ float rcp_(float x) { return __builtin_amdgcn_rcpf(x); }
__device__ __forceinline__ float sigmoidf_(float x) { return rcp_(1.0f + __expf(-x)); }
__device__ __forceinline__ float tanhf_(float x) {
    float e2 = __expf(x + x);
    return 1.0f - 2.0f * rcp_(1.0f + e2);
}

// ---- VOP3P packed f32 (2 IEEE f32 ops per issue slot; hipcc won't auto-emit) ----
__device__ __forceinline__ f32x2 pk_fma(f32x2 a, f32x2 b, f32x2 c) {
    f32x2 d;
    asm("v_pk_fma_f32 %0, %1, %2, %3" : "=v"(d) : "v"(a), "v"(b), "v"(c));
    return d;
}
__device__ __forceinline__ f32x2 pk_add(f32x2 a, f32x2 b) {
    f32x2 d;
    asm("v_pk_add_f32 %0, %1, %2" : "=v"(d) : "v"(a), "v"(b));
    return d;
}
__device__ __forceinline__ f32x2 pk_mul(f32x2 a, f32x2 b) {
    f32x2 d;
    asm("v_pk_mul_f32 %0, %1, %2" : "=v"(d) : "v"(a), "v"(b));
    return d;
}

// pack 4 floats -> 4 fp8 e4m3 bytes (little-endian order v0..v3)
__device__ __forceinline__ unsigned pk4_fp8(float v0, float v1, float v2, float v3) {
    int w = 0;
    w = __builtin_amdgcn_cvt_pk_fp8_f32(v0, v1, w, false);
    w = __builtin_amdgcn_cvt_pk_fp8_f32(v2, v3, w, true);
    return (unsigned)w;
}
#define PIN64(v) asm volatile("" : "+v"(v))

// ---------------- prep: U matrices -> fp8 MFMA A-fragment layout ----------------
// A-frag for (gate, col-tile ct, kt): lane holds 8 fp8 of A[m][k] = U[k][col],
// col = ct*16 + (lane&15), k = kt*32 + (lane>>4)*8 + j (j = byte 0..7).
__global__ __launch_bounds__(256) void prep_kernel(const float* __restrict__ Uz,
                                                   const float* __restrict__ Ur,
                                                   const float* __restrict__ Uh,
                                                   uint2* __restrict__ UB) {
    int tid  = blockIdx.x * 256 + threadIdx.x;   // 0 .. 24575
    int gate = tid >> 13;                         // 3 gates x 8192
    int rem  = tid & 8191;
    int ct   = rem >> 9;                          // 0..15
    int kt   = (rem >> 6) & 7;                    // 0..7
    int lane = rem & 63;
    int col  = ct * 16 + (lane & 15);
    int kb   = kt * 32 + (lane >> 4) * 8;
    const float* src = (gate == 0) ? Uz : (gate == 1) ? Ur : Uh;
    float f[8];
#pragma unroll
    for (int j = 0; j < 8; ++j) f[j] = src[(kb + j) * HH + col];
    uint2 v;
    v.x = pk4_fp8(f[0], f[1], f[2], f[3]);
    v.y = pk4_fp8(f[4], f[5], f[6], f[7]);
    UB[tid] = v;
}

// ---------------- persistent GRU: 1 WG = 16 rows, 16 waves, 4 waves/SIMD ----------------
// R10 post-mortem: VALU-issue saturated (75% busy/active CU); scalar diet gave
// only 1.5%. This round: elementwise rewritten in PACKED f32 (v_pk_fma/add/mul
// via inline asm) — the affine/blend/mul scaffolding halves its issue slots.
// exp/rcp remain scalar (no packed trans pipe). Bit-identical arithmetic
// (v_pk_fma_f32 = 2x IEEE fma), same accumulation order as R9/R10.
//
// Wave w owns m-tile w (U-cols [16w,16w+16)), 3 gates: 24 frags x 2 = 48 regs
// (AGPR-resident, read natively by MFMA).
// Thread owns batch row n = lane&15, cols 16w + lg*4 + i.
// h/rh fp8 PAIRED B-frag layout: element (k,n) at byte
//   (k>>6)*1024 + (n + 16*((k>>3)&3))*16 + ((k>>5)&1)*8 + (k&7)
// Writer (w,lg,n): one b32 at
//   (w>>2)*1024 + (n + 16*((2w+(lg>>1))&3))*16 + ((w>>1)&1)*8 + (lg&1)*4
// Reader lane l, pair p: b128 at p*1024 + l*16 -> (kt=2p, kt=2p+1) fragments.
//
// LDS map (bytes):
//   0     : hB buf0  (4 KB)
//   4096  : hB buf1  (4 KB)
//   8192  : rhB      (4 KB)
//   12288 : params   (8 KB)  8 planes x 256 f32 (read ONCE pre-loop)
//   20480 : xs       (16.07 KB) 16 rows x 1028 B
//   36928 : sigL     (64 B)
//   epilogue overlays: hsF f32[16][256] at 0, hid f32[16][256] at 16384
__global__ __launch_bounds__(1024) __attribute__((amdgpu_waves_per_eu(4, 4))) void gru_kernel(
    const float* __restrict__ x,
    const float* __restrict__ Wzw, const float* __restrict__ Wzb, const float* __restrict__ Uzb,
    const float* __restrict__ Wrw, const float* __restrict__ Wrb, const float* __restrict__ Urb,
    const float* __restrict__ Whw, const float* __restrict__ Whb, const float* __restrict__ Uhb,
    const float* __restrict__ Wgw, const float* __restrict__ Wgb,
    const float* __restrict__ om_raw, const float* __restrict__ al_raw,
    const float* __restrict__ be_raw, const float* __restrict__ gam,
    const float* __restrict__ fc1w, const float* __restrict__ fc1b,
    const float* __restrict__ fc2w, const float* __restrict__ fc2b,
    const long* __restrict__ UBL,
    float* __restrict__ out) {

    __shared__ __align__(16) char lds[36992];

    const int t    = threadIdx.x;
    const int w    = t >> 6;        // wave 0..15, owns m-tile w
    const int lane = t & 63;
    const int n    = lane & 15;     // owned batch row
    const int lg   = lane >> 4;     // lane group 0..3
    const int b0   = blockIdx.x * ROWS;

    // ---- weights: 48 regs of fp8 fragments (land in AGPRs) ----
    long Wz[8], Wr[8], Wh[8];
#pragma unroll
    for (int kt = 0; kt < 8; ++kt) {
        Wz[kt] = UBL[((0 * 16 + w) * 8 + kt) * 64 + lane];
        Wr[kt] = UBL[((1 * 16 + w) * 8 + kt) * 64 + lane];
        Wh[kt] = UBL[((2 * 16 + w) * 8 + kt) * 64 + lane];
    }
#pragma unroll
    for (int kt = 0; kt < 8; ++kt) { PIN64(Wz[kt]); PIN64(Wr[kt]); PIN64(Wh[kt]); }

    // ---- stage x rows (padded 1028B stride) ----
#pragma unroll
    for (int it = 0; it < 4; ++it) {
        int i = t + it * 1024;                  // 0..4095
        int r = i >> 8, tp = i & 255;
        *(float*)(lds + 20480 + r * 1028 + tp * 4) = x[(b0 + r) * TT + tp];
    }
    // ---- per-column param table (consumed once, right below) ----
#pragma unroll
    for (int it = 0; it < 2; ++it) {
        int i = t + it * 1024;                  // 0..2047
        int p = i >> 8, c = i & 255;
        float v;
        switch (p) {
            case 0: v = Wzw[c]; break;
            case 1: v = Wzb[c] + Uzb[c]; break;
            case 2: v = Wrw[c]; break;
            case 3: v = Wrb[c] + Urb[c]; break;
            case 4: v = Whw[c]; break;
            case 5: v = Whb[c] + Uhb[c]; break;
            case 6: v = Wgw[c]; break;
            default: v = Wgb[c]; break;
        }
        *(float*)(lds + 12288 + p * 1024 + c * 4) = v;
    }
    // ---- zero h buffer 0 ----
    ((unsigned*)lds)[t] = 0;

    // scalar params (uniform -> SGPRs)
    const float omega = log1pf(__expf(om_raw[0])) + 1e-6f;
    const float aco   = sigmoidf_(al_raw[0]);
    const float bco   = sigmoidf_(be_raw[0]) * (1.0f - aco * 0.99f);
    const float gma   = gam[0];

    // address bases
    const int rdF = lane * 16;                                                 // + buf + p*1024
    const int wrB = (w >> 2) * 1024 + (n + 16 * ((2 * w + (lg >> 1)) & 3)) * 16
                  + ((w >> 1) & 1) * 8 + (lg & 1) * 4;
    const int pvB = 12288 + w * 64 + lg * 16;                                  // + p*1024
    const int xvB = 20480 + n * 1028;                                          // + tt*4

    __syncthreads();

    // ---- hoist params into registers as f32x2 halves (loop-invariant) ----
    const f32x2 wz_a = *(const f32x2*)(lds + pvB + 0 * 1024);
    const f32x2 wz_b = *(const f32x2*)(lds + pvB + 0 * 1024 + 8);
    const f32x2 bz_a = *(const f32x2*)(lds + pvB + 1 * 1024);
    const f32x2 bz_b = *(const f32x2*)(lds + pvB + 1 * 1024 + 8);
    const f32x2 wr_a = *(const f32x2*)(lds + pvB + 2 * 1024);
    const f32x2 wr_b = *(const f32x2*)(lds + pvB + 2 * 1024 + 8);
    const f32x2 br_a = *(const f32x2*)(lds + pvB + 3 * 1024);
    const f32x2 br_b = *(const f32x2*)(lds + pvB + 3 * 1024 + 8);
    const f32x2 wh_a = *(const f32x2*)(lds + pvB + 4 * 1024);
    const f32x2 wh_b = *(const f32x2*)(lds + pvB + 4 * 1024 + 8);
    const f32x2 bh_a = *(const f32x2*)(lds + pvB + 5 * 1024);
    const f32x2 bh_b = *(const f32x2*)(lds + pvB + 5 * 1024 + 8);
    const f32x2 wg_a = *(const f32x2*)(lds + pvB + 6 * 1024);
    const f32x2 wg_b = *(const f32x2*)(lds + pvB + 6 * 1024 + 8);
    const f32x2 bg_a = *(const f32x2*)(lds + pvB + 7 * 1024);
    const f32x2 bg_b = *(const f32x2*)(lds + pvB + 7 * 1024 + 8);

    // packed constants (VOP3P takes no literals — keep in regs)
    const f32x2 one2 = {1.0f, 1.0f};
    const f32x2 m2_2 = {-2.0f, -2.0f};
    const f32x2 n1_2 = {-1.0f, -1.0f};
    const f32x2 gma2 = {gma, gma};

    f32x2 h_a = {0.f, 0.f}, h_b = {0.f, 0.f};
    f32x2 zst_a, zst_b;
    float sg = 1e-6f, xp = 0.f;

    int hb = 0;
    for (int tt = 0; tt < TT; ++tt) {
        const float xc = *(const float*)(lds + xvB + tt * 4);
        const f32x2 xc2 = {xc, xc};

        // ---- phase A: Cz = h@Uz, Cr = h@Ur (4 x b128, paired fragments) ----
        f32x4 Cz = (f32x4){0.f, 0.f, 0.f, 0.f};
        f32x4 Cr = (f32x4){0.f, 0.f, 0.f, 0.f};
#pragma unroll
        for (int p = 0; p < 4; ++p) {
            lpair hv = *(const lpair*)(lds + hb + rdF + p * 1024);
            Cz = __builtin_amdgcn_mfma_f32_16x16x32_fp8_fp8(Wz[2 * p],     hv.x, Cz, 0, 0, 0);
            Cz = __builtin_amdgcn_mfma_f32_16x16x32_fp8_fp8(Wz[2 * p + 1], hv.y, Cz, 0, 0, 0);
            Cr = __builtin_amdgcn_mfma_f32_16x16x32_fp8_fp8(Wr[2 * p],     hv.x, Cr, 0, 0, 0);
            Cr = __builtin_amdgcn_mfma_f32_16x16x32_fp8_fp8(Wr[2 * p + 1], hv.y, Cr, 0, 0, 0);
        }
        // elementwise z, r (packed); write r*h (fp8, one b32)
        {
            f32x2 cz_a = {Cz[0], Cz[1]}, cz_b = {Cz[2], Cz[3]};
            f32x2 cr_a = {Cr[0], Cr[1]}, cr_b = {Cr[2], Cr[3]};
            f32x2 az_a = pk_add(pk_fma(xc2, wz_a, bz_a), cz_a);
            f32x2 az_b = pk_add(pk_fma(xc2, wz_b, bz_b), cz_b);
            f32x2 ar_a = pk_add(pk_fma(xc2, wr_a, br_a), cr_a);
            f32x2 ar_b = pk_add(pk_fma(xc2, wr_b, br_b), cr_b);
            f32x2 ez_a = {__expf(-az_a.x), __expf(-az_a.y)};
            f32x2 ez_b = {__expf(-az_b.x), __expf(-az_b.y)};
            f32x2 er_a = {__expf(-ar_a.x), __expf(-ar_a.y)};
            f32x2 er_b = {__expf(-ar_b.x), __expf(-ar_b.y)};
            ez_a = pk_add(ez_a, one2); ez_b = pk_add(ez_b, one2);
            er_a = pk_add(er_a, one2); er_b = pk_add(er_b, one2);
            zst_a = (f32x2){rcp_(ez_a.x), rcp_(ez_a.y)};
            zst_b = (f32x2){rcp_(ez_b.x), rcp_(ez_b.y)};
            f32x2 r_a = {rcp_(er_a.x), rcp_(er_a.y)};
            f32x2 r_b = {rcp_(er_b.x), rcp_(er_b.y)};
            f32x2 rh_a = pk_mul(r_a, h_a);
            f32x2 rh_b = pk_mul(r_b, h_b);
            *(unsigned*)(lds + 8192 + wrB) = pk4_fp8(rh_a.x, rh_a.y, rh_b.x, rh_b.y);
        }
        __syncthreads();

        // ---- phase B: Ch = (r*h)@Uh ----
        f32x4 Ch = (f32x4){0.f, 0.f, 0.f, 0.f};
#pragma unroll
        for (int p = 0; p < 4; ++p) {
            lpair rv8 = *(const lpair*)(lds + 8192 + rdF + p * 1024);
            Ch = __builtin_amdgcn_mfma_f32_16x16x32_fp8_fp8(Wh[2 * p],     rv8.x, Ch, 0, 0, 0);
            Ch = __builtin_amdgcn_mfma_f32_16x16x32_fp8_fp8(Wh[2 * p + 1], rv8.y, Ch, 0, 0, 0);
        }
        // garch recurrence (row-n scalar; uses x[tt-1])
        float ep = (tt == 0) ? 1e-6f : xp * xp;
        float gv = omega + aco * ep + bco * sg;
        sg = gv;
        // elementwise h_new (packed); write h (fp8, other buffer)
        {
            f32x2 ch_a = {Ch[0], Ch[1]}, ch_b = {Ch[2], Ch[3]};
            f32x2 ah_a = pk_add(pk_fma(xc2, wh_a, bh_a), ch_a);
            f32x2 ah_b = pk_add(pk_fma(xc2, wh_b, bh_b), ch_b);
            // tanh(y) = 1 - 2*rcp(1 + e^{2y})
            f32x2 y_a = pk_add(ah_a, ah_a), y_b = pk_add(ah_b, ah_b);
            f32x2 eh_a = {__expf(y_a.x), __expf(y_a.y)};
            f32x2 eh_b = {__expf(y_b.x), __expf(y_b.y)};
            eh_a = pk_add(eh_a, one2); eh_b = pk_add(eh_b, one2);
            f32x2 q_a = {rcp_(eh_a.x), rcp_(eh_a.y)};
            f32x2 q_b = {rcp_(eh_b.x), rcp_(eh_b.y)};
            f32x2 htld_a = pk_fma(q_a, m2_2, one2);
            f32x2 htld_b = pk_fma(q_b, m2_2, one2);
            // hh = htld + z*(h - htld)
            f32x2 d_a = pk_fma(htld_a, n1_2, h_a);
            f32x2 d_b = pk_fma(htld_b, n1_2, h_b);
            f32x2 hh_a = pk_fma(zst_a, d_a, htld_a);
            f32x2 hh_b = pk_fma(zst_b, d_b, htld_b);
            // arg = hh + gma*(gv*wg + bg)
            f32x2 gv2 = {gv, gv};
            f32x2 gt_a = pk_fma(gv2, wg_a, bg_a);
            f32x2 gt_b = pk_fma(gv2, wg_b, bg_b);
            f32x2 a2_a = pk_fma(gma2, gt_a, hh_a);
            f32x2 a2_b = pk_fma(gma2, gt_b, hh_b);
            f32x2 y2_a = pk_add(a2_a, a2_a), y2_b = pk_add(a2_b, a2_b);
            f32x2 en_a = {__expf(y2_a.x), __expf(y2_a.y)};
            f32x2 en_b = {__expf(y2_b.x), __expf(y2_b.y)};
            en_a = pk_add(en_a, one2); en_b = pk_add(en_b, one2);
            f32x2 p_a = {rcp_(en_a.x), rcp_(en_a.y)};
            f32x2 p_b = {rcp_(en_b.x), rcp_(en_b.y)};
            h_a = pk_fma(p_a, m2_2, one2);
            h_b = pk_fma(p_b, m2_2, one2);
            *(unsigned*)(lds + (hb ^ 4096) + wrB) = pk4_fp8(h_a.x, h_a.y, h_b.x, h_b.y);
        }
        xp = xc;
        hb ^= 4096;
        __syncthreads();
    }

    // ---- stash exact fp32 h (overlay, 16 KB at 0) + sigma_sq ----
    {
        float* hsF = (float*)lds;
        hsF[n * 256 + 16 * w + lg * 4 + 0] = h_a.x;
        hsF[n * 256 + 16 * w + lg * 4 + 1] = h_a.y;
        hsF[n * 256 + 16 * w + lg * 4 + 2] = h_b.x;
        hsF[n * 256 + 16 * w + lg * 4 + 3] = h_b.y;
        if (w == 0 && lg == 0) ((float*)(lds + 36928))[n] = sg;
    }
    __syncthreads();

    // ---- head: hid = relu(h @ fc1 + b1) ----
    {
        const int j = t & 255, q = t >> 8;      // q: rows q*4 .. +3
        const float* hsF = (const float*)lds;
        float acc[4];
#pragma unroll
        for (int r = 0; r < 4; ++r) acc[r] = 0.f;
#pragma unroll 4
        for (int k = 0; k < HH; ++k) {
            float wv = fc1w[k * HH + j];
#pragma unroll
            for (int r = 0; r < 4; ++r) acc[r] += hsF[(q * 4 + r) * 256 + k] * wv;
        }
        float* hid = (float*)(lds + 16384);
        const float b1 = fc1b[j];
#pragma unroll
        for (int r = 0; r < 4; ++r) hid[(q * 4 + r) * 256 + j] = fmaxf(acc[r] + b1, 0.f);
    }
    __syncthreads();

    // ---- head: nn_scale / vol ----
    if (t < ROWS * HOR) {
        const int b = t / HOR, c = t % HOR;
        const float* hid = (const float*)(lds + 16384);
        float acc = fc2b[c];
        for (int k = 0; k < HH; ++k) acc += hid[b * 256 + k] * fc2w[k * HOR + c];
        const float sp  = log1pf(__expf(acc));
        const float sgv = ((const float*)(lds + 36928))[b];
        const float vb  = sqrtf(sgv + 1e-8f);
        float vol = vb * (1.0f + sp);
        vol = fminf(fmaxf(vol, 0.01f), 10.0f);
        out[(b0 + b) * HOR + c] = vol;
    }
    if (t < ROWS) out[BATCH * HOR + b0 + t] = ((const float*)(lds + 36928))[t];
}

extern "C" void kernel_launch(void* const* d_in, const int* in_sizes, int n_in,
                              void* d_out, int out_size, void* d_ws, size_t ws_size,
                              hipStream_t stream) {
    const float* x    = (const float*)d_in[0];
    const float* Wzw  = (const float*)d_in[1];
    const float* Wzb  = (const float*)d_in[2];
    const float* Uzw  = (const float*)d_in[3];
    const float* Uzb  = (const float*)d_in[4];
    const float* Wrw  = (const float*)d_in[5];
    const float* Wrb  = (const float*)d_in[6];
    const float* Urw  = (const float*)d_in[7];
    const float* Urb  = (const float*)d_in[8];
    const float* Whw  = (const float*)d_in[9];
    const float* Whb  = (const float*)d_in[10];
    const float* Uhw  = (const float*)d_in[11];
    const float* Uhb  = (const float*)d_in[12];
    const float* Wgw  = (const float*)d_in[13];
    const float* Wgb  = (const float*)d_in[14];
    const float* om   = (const float*)d_in[15];
    const float* al   = (const float*)d_in[16];
    const float* be   = (const float*)d_in[17];
    const float* ga   = (const float*)d_in[18];
    const float* fc1w = (const float*)d_in[19];
    const float* fc1b = (const float*)d_in[20];
    const float* fc2w = (const float*)d_in[21];
    const float* fc2b = (const float*)d_in[22];

    uint2* UB = (uint2*)d_ws;   // 24576 x 8B fp8 fragments = 192 KB

    prep_kernel<<<96, 256, 0, stream>>>(Uzw, Urw, Uhw, UB);
    gru_kernel<<<32, 1024, 0, stream>>>(x, Wzw, Wzb, Uzb, Wrw, Wrb, Urb, Whw, Whb, Uhb,
                                        Wgw, Wgb, om, al, be, ga, fc1w, fc1b, fc2w, fc2b,
                                        (const long*)UB, (float*)d_out);
}

// Round 12
// 538.200 us; speedup vs baseline: 1.0824x; 1.0824x over previous
//
#include <hip/hip_runtime.h>

#define BATCH 512
#define TT 256
#define HH 256
#define HOR 22
#define ROWS 16

typedef __attribute__((ext_vector_type(4))) float f32x4;
// 16-byte aligned pair of 64-bit fragments (aligned 16B aggregate load -> ds_read_b128)
struct __align__(16) lpair { long x, y; };

__device__ __forceinline__ float rcp_(float x) { return __builtin_amdgcn_rcpf(x); }
__device__ __forceinline__ float sigmoidf_(float x) { return rcp_(1.0f + __expf(-x)); }

#if defined(__has_builtin)
#if __has_builtin(__builtin_amdgcn_exp2f)
#define EXP2F(v) __builtin_amdgcn_exp2f(v)
#endif
#endif
#ifndef EXP2F
#define EXP2F(v) exp2f(v)
#endif
// tanh(x) = 1 - 2/(2^(x*2log2e)+1): mul+exp+add+rcp+fma (the x2 folded into
// the exp2 constant — one inst less than the exp(2x) form).
__device__ __forceinline__ float tanhf_(float x) {
    float e2 = EXP2F(x * 2.8853900817779268f);
    return 1.0f - 2.0f * rcp_(1.0f + e2);
}
// pack 4 floats -> 4 fp8 e4m3 bytes (little-endian order v0..v3)
__device__ __forceinline__ unsigned pk4_fp8(float v0, float v1, float v2, float v3) {
    int w = 0;
    w = __builtin_amdgcn_cvt_pk_fp8_f32(v0, v1, w, false);
    w = __builtin_amdgcn_cvt_pk_fp8_f32(v2, v3, w, true);
    return (unsigned)w;
}
#define PIN64(v) asm volatile("" : "+v"(v))

// ---------------- prep: U matrices -> fp8 MFMA A-fragment layout ----------------
// A-frag for (gate, col-tile ct, kt): lane holds 8 fp8 of A[m][k] = U[k][col],
// col = ct*16 + (lane&15), k = kt*32 + (lane>>4)*8 + j (j = byte 0..7).
__global__ __launch_bounds__(256) void prep_kernel(const float* __restrict__ Uz,
                                                   const float* __restrict__ Ur,
                                                   const float* __restrict__ Uh,
                                                   uint2* __restrict__ UB) {
    int tid  = blockIdx.x * 256 + threadIdx.x;   // 0 .. 24575
    int gate = tid >> 13;                         // 3 gates x 8192
    int rem  = tid & 8191;
    int ct   = rem >> 9;                          // 0..15
    int kt   = (rem >> 6) & 7;                    // 0..7
    int lane = rem & 63;
    int col  = ct * 16 + (lane & 15);
    int kb   = kt * 32 + (lane >> 4) * 8;
    const float* src = (gate == 0) ? Uz : (gate == 1) ? Ur : Uh;
    float f[8];
#pragma unroll
    for (int j = 0; j < 8; ++j) f[j] = src[(kb + j) * HH + col];
    uint2 v;
    v.x = pk4_fp8(f[0], f[1], f[2], f[3]);
    v.y = pk4_fp8(f[4], f[5], f[6], f[7]);
    UB[tid] = v;
}

// ---------------- persistent GRU: 1 WG = 16 rows, 16 waves, 4 waves/SIMD ----------------
// R11 post-mortem: packed-f32 asm cut VALU issue (75->59%) but destroyed the
// compiler's MFMA/VALU cross-pipe overlap (sum 110% -> 92%) — net regression.
// This round: R10 scalar structure restored, plus BIAS-PRELOADED accumulators:
// C[i] = fma(xc, w[i], b[i]) computed BEFORE the MFMA chain (MFMA carries C
// through). Deletes the post-chain adds and moves the affine work + garch into
// the MFMA shadow, shortening the serial post-chain VALU burst. tanh uses
// native exp2 (x2 folded into the constant).
//
// Wave w owns m-tile w (U-cols [16w,16w+16)), 3 gates: 24 frags x 2 = 48 regs
// (AGPR-resident, read natively by MFMA).
// Thread owns batch row n = lane&15, cols 16w + lg*4 + i.
// h/rh fp8 PAIRED B-frag layout: element (k,n) at byte
//   (k>>6)*1024 + (n + 16*((k>>3)&3))*16 + ((k>>5)&1)*8 + (k&7)
// Writer (w,lg,n): one b32 at
//   (w>>2)*1024 + (n + 16*((2w+(lg>>1))&3))*16 + ((w>>1)&1)*8 + (lg&1)*4
// Reader lane l, pair p: b128 at p*1024 + l*16 -> (kt=2p, kt=2p+1) fragments.
//
// LDS map (bytes):
//   0     : hB buf0  (4 KB)
//   4096  : hB buf1  (4 KB)
//   8192  : rhB      (4 KB)
//   12288 : params   (8 KB)  8 planes x 256 f32 (read ONCE pre-loop)
//   20480 : xs       (16.07 KB) 16 rows x 1028 B
//   36928 : sigL     (64 B)
//   epilogue overlays: hsF f32[16][256] at 0, hid f32[16][256] at 16384
__global__ __launch_bounds__(1024) __attribute__((amdgpu_waves_per_eu(4, 4))) void gru_kernel(
    const float* __restrict__ x,
    const float* __restrict__ Wzw, const float* __restrict__ Wzb, const float* __restrict__ Uzb,
    const float* __restrict__ Wrw, const float* __restrict__ Wrb, const float* __restrict__ Urb,
    const float* __restrict__ Whw, const float* __restrict__ Whb, const float* __restrict__ Uhb,
    const float* __restrict__ Wgw, const float* __restrict__ Wgb,
    const float* __restrict__ om_raw, const float* __restrict__ al_raw,
    const float* __restrict__ be_raw, const float* __restrict__ gam,
    const float* __restrict__ fc1w, const float* __restrict__ fc1b,
    const float* __restrict__ fc2w, const float* __restrict__ fc2b,
    const long* __restrict__ UBL,
    float* __restrict__ out) {

    __shared__ __align__(16) char lds[36992];

    const int t    = threadIdx.x;
    const int w    = t >> 6;        // wave 0..15, owns m-tile w
    const int lane = t & 63;
    const int n    = lane & 15;     // owned batch row
    const int lg   = lane >> 4;     // lane group 0..3
    const int b0   = blockIdx.x * ROWS;

    // ---- weights: 48 regs of fp8 fragments (land in AGPRs) ----
    long Wz[8], Wr[8], Wh[8];
#pragma unroll
    for (int kt = 0; kt < 8; ++kt) {
        Wz[kt] = UBL[((0 * 16 + w) * 8 + kt) * 64 + lane];
        Wr[kt] = UBL[((1 * 16 + w) * 8 + kt) * 64 + lane];
        Wh[kt] = UBL[((2 * 16 + w) * 8 + kt) * 64 + lane];
    }
#pragma unroll
    for (int kt = 0; kt < 8; ++kt) { PIN64(Wz[kt]); PIN64(Wr[kt]); PIN64(Wh[kt]); }

    // ---- stage x rows (padded 1028B stride) ----
#pragma unroll
    for (int it = 0; it < 4; ++it) {
        int i = t + it * 1024;                  // 0..4095
        int r = i >> 8, tp = i & 255;
        *(float*)(lds + 20480 + r * 1028 + tp * 4) = x[(b0 + r) * TT + tp];
    }
    // ---- per-column param table (consumed once, right below) ----
#pragma unroll
    for (int it = 0; it < 2; ++it) {
        int i = t + it * 1024;                  // 0..2047
        int p = i >> 8, c = i & 255;
        float v;
        switch (p) {
            case 0: v = Wzw[c]; break;
            case 1: v = Wzb[c] + Uzb[c]; break;
            case 2: v = Wrw[c]; break;
            case 3: v = Wrb[c] + Urb[c]; break;
            case 4: v = Whw[c]; break;
            case 5: v = Whb[c] + Uhb[c]; break;
            case 6: v = Wgw[c]; break;
            default: v = Wgb[c]; break;
        }
        *(float*)(lds + 12288 + p * 1024 + c * 4) = v;
    }
    // ---- zero h buffer 0 ----
    ((unsigned*)lds)[t] = 0;

    // scalar params (uniform -> SGPRs)
    const float omega = log1pf(__expf(om_raw[0])) + 1e-6f;
    const float aco   = sigmoidf_(al_raw[0]);
    const float bco   = sigmoidf_(be_raw[0]) * (1.0f - aco * 0.99f);
    const float gma   = gam[0];

    // address bases
    const int rdF = lane * 16;                                                 // + buf + p*1024
    const int wrB = (w >> 2) * 1024 + (n + 16 * ((2 * w + (lg >> 1)) & 3)) * 16
                  + ((w >> 1) & 1) * 8 + (lg & 1) * 4;
    const int pvB = 12288 + w * 64 + lg * 16;                                  // + p*1024
    const int xvB = 20480 + n * 1028;                                          // + tt*4

    __syncthreads();

    // ---- hoist params into registers (loop-invariant) ----
    const f32x4 wzv = *(const f32x4*)(lds + pvB + 0 * 1024);
    const f32x4 bzv = *(const f32x4*)(lds + pvB + 1 * 1024);
    const f32x4 wrv = *(const f32x4*)(lds + pvB + 2 * 1024);
    const f32x4 brv = *(const f32x4*)(lds + pvB + 3 * 1024);
    const f32x4 whv = *(const f32x4*)(lds + pvB + 4 * 1024);
    const f32x4 bhv = *(const f32x4*)(lds + pvB + 5 * 1024);
    const f32x4 wgv = *(const f32x4*)(lds + pvB + 6 * 1024);
    const f32x4 bgv = *(const f32x4*)(lds + pvB + 7 * 1024);

    f32x4 h_own = (f32x4){0.f, 0.f, 0.f, 0.f};
    f32x4 zst;
    float sg = 1e-6f, xp = 0.f;

    int hb = 0;
    for (int tt = 0; tt < TT; ++tt) {
        const float xc = *(const float*)(lds + xvB + tt * 4);

        // ---- phase A: Cz/Cr accumulators preloaded with affine term, then
        //      8 chained MFMAs each (bias rides in the C operand) ----
        f32x4 Cz, Cr;
#pragma unroll
        for (int i = 0; i < 4; ++i) {
            Cz[i] = fmaf(xc, wzv[i], bzv[i]);
            Cr[i] = fmaf(xc, wrv[i], brv[i]);
        }
#pragma unroll
        for (int p = 0; p < 4; ++p) {
            lpair hv = *(const lpair*)(lds + hb + rdF + p * 1024);
            Cz = __builtin_amdgcn_mfma_f32_16x16x32_fp8_fp8(Wz[2 * p],     hv.x, Cz, 0, 0, 0);
            Cz = __builtin_amdgcn_mfma_f32_16x16x32_fp8_fp8(Wz[2 * p + 1], hv.y, Cz, 0, 0, 0);
            Cr = __builtin_amdgcn_mfma_f32_16x16x32_fp8_fp8(Wr[2 * p],     hv.x, Cr, 0, 0, 0);
            Cr = __builtin_amdgcn_mfma_f32_16x16x32_fp8_fp8(Wr[2 * p + 1], hv.y, Cr, 0, 0, 0);
        }
        // elementwise z, r; write r*h (fp8, one b32)
        {
            float rh[4];
#pragma unroll
            for (int i = 0; i < 4; ++i) {
                zst[i]   = sigmoidf_(Cz[i]);
                float rv = sigmoidf_(Cr[i]);
                rh[i]    = rv * h_own[i];
            }
            *(unsigned*)(lds + 8192 + wrB) = pk4_fp8(rh[0], rh[1], rh[2], rh[3]);
        }
        __syncthreads();

        // ---- phase B: garch + affine preload in MFMA shadow, then Ch chain ----
        float ep = (tt == 0) ? 1e-6f : xp * xp;
        float gv = omega + aco * ep + bco * sg;
        sg = gv;
        f32x4 Ch, gq;
#pragma unroll
        for (int i = 0; i < 4; ++i) {
            Ch[i] = fmaf(xc, whv[i], bhv[i]);
            gq[i] = gma * fmaf(gv, wgv[i], bgv[i]);
        }
#pragma unroll
        for (int p = 0; p < 4; ++p) {
            lpair rv8 = *(const lpair*)(lds + 8192 + rdF + p * 1024);
            Ch = __builtin_amdgcn_mfma_f32_16x16x32_fp8_fp8(Wh[2 * p],     rv8.x, Ch, 0, 0, 0);
            Ch = __builtin_amdgcn_mfma_f32_16x16x32_fp8_fp8(Wh[2 * p + 1], rv8.y, Ch, 0, 0, 0);
        }
        // elementwise h_new; write h (fp8, other buffer)
        {
            float hn[4];
#pragma unroll
            for (int i = 0; i < 4; ++i) {
                float htld = tanhf_(Ch[i]);
                // h_hat = (1-z)*htld + z*h  ==  htld + z*(h - htld)
                float hh   = htld + zst[i] * (h_own[i] - htld);
                hn[i]      = tanhf_(hh + gq[i]);
                h_own[i]   = hn[i];
            }
            *(unsigned*)(lds + (hb ^ 4096) + wrB) = pk4_fp8(hn[0], hn[1], hn[2], hn[3]);
        }
        xp = xc;
        hb ^= 4096;
        __syncthreads();
    }

    // ---- stash exact fp32 h (overlay, 16 KB at 0) + sigma_sq ----
    {
        float* hsF = (float*)lds;
#pragma unroll
        for (int i = 0; i < 4; ++i)
            hsF[n * 256 + 16 * w + lg * 4 + i] = h_own[i];
        if (w == 0 && lg == 0) ((float*)(lds + 36928))[n] = sg;
    }
    __syncthreads();

    // ---- head: hid = relu(h @ fc1 + b1) ----
    {
        const int j = t & 255, q = t >> 8;      // q: rows q*4 .. +3
        const float* hsF = (const float*)lds;
        float acc[4];
#pragma unroll
        for (int r = 0; r < 4; ++r) acc[r] = 0.f;
#pragma unroll 4
        for (int k = 0; k < HH; ++k) {
            float wv = fc1w[k * HH + j];
#pragma unroll
            for (int r = 0; r < 4; ++r) acc[r] += hsF[(q * 4 + r) * 256 + k] * wv;
        }
        float* hid = (float*)(lds + 16384);
        const float b1 = fc1b[j];
#pragma unroll
        for (int r = 0; r < 4; ++r) hid[(q * 4 + r) * 256 + j] = fmaxf(acc[r] + b1, 0.f);
    }
    __syncthreads();

    // ---- head: nn_scale / vol ----
    if (t < ROWS * HOR) {
        const int b = t / HOR, c = t % HOR;
        const float* hid = (const float*)(lds + 16384);
        float acc = fc2b[c];
        for (int k = 0; k < HH; ++k) acc += hid[b * 256 + k] * fc2w[k * HOR + c];
        const float sp  = log1pf(__expf(acc));
        const float sgv = ((const float*)(lds + 36928))[b];
        const float vb  = sqrtf(sgv + 1e-8f);
        float vol = vb * (1.0f + sp);
        vol = fminf(fmaxf(vol, 0.01f), 10.0f);
        out[(b0 + b) * HOR + c] = vol;
    }
    if (t < ROWS) out[BATCH * HOR + b0 + t] = ((const float*)(lds + 36928))[t];
}

extern "C" void kernel_launch(void* const* d_in, const int* in_sizes, int n_in,
                              void* d_out, int out_size, void* d_ws, size_t ws_size,
                              hipStream_t stream) {
    const float* x    = (const float*)d_in[0];
    const float* Wzw  = (const float*)d_in[1];
    const float* Wzb  = (const float*)d_in[2];
    const float* Uzw  = (const float*)d_in[3];
    const float* Uzb  = (const float*)d_in[4];
    const float* Wrw  = (const float*)d_in[5];
    const float* Wrb  = (const float*)d_in[6];
    const float* Urw  = (const float*)d_in[7];
    const float* Urb  = (const float*)d_in[8];
    const float* Whw  = (const float*)d_in[9];
    const float* Whb  = (const float*)d_in[10];
    const float* Uhw  = (const float*)d_in[11];
    const float* Uhb  = (const float*)d_in[12];
    const float* Wgw  = (const float*)d_in[13];
    const float* Wgb  = (const float*)d_in[14];
    const float* om   = (const float*)d_in[15];
    const float* al   = (const float*)d_in[16];
    const float* be   = (const float*)d_in[17];
    const float* ga   = (const float*)d_in[18];
    const float* fc1w = (const float*)d_in[19];
    const float* fc1b = (const float*)d_in[20];
    const float* fc2w = (const float*)d_in[21];
    const float* fc2b = (const float*)d_in[22];

    uint2* UB = (uint2*)d_ws;   // 24576 x 8B fp8 fragments = 192 KB

    prep_kernel<<<96, 256, 0, stream>>>(Uzw, Urw, Uhw, UB);
    gru_kernel<<<32, 1024, 0, stream>>>(x, Wzw, Wzb, Uzb, Wrw, Wrb, Urb, Whw, Whb, Uhb,
                                        Wgw, Wgb, om, al, be, ga, fc1w, fc1b, fc2w, fc2b,
                                        (const long*)UB, (float*)d_out);
}